// Round 4
// baseline (4380.423 us; speedup 1.0000x reference)
//
#include <hip/hip_runtime.h>

typedef _Float16 half2_t __attribute__((ext_vector_type(2)));

#define NB 64
#define NT 2048
#define ND 256
#define NH 256
#define NTHR 1024
#define CHUNK 32
#define NCHUNK (NT / CHUNK)   // 64

// consumer LDS layout (half2 = 4B units):
//   whhT : 256 cols * 132 (128 k-pairs + 4 pad)  = 33792 units (132 KB)
//   hb   : 4 quarters * 36 (32 + 4 pad)          = 144 units
//   vb   : 144 units
#define WHH_STRIDE 132
#define HV_STRIDE  36
#define LDS_UNITS  (256 * WHH_STRIDE + 2 * 144)

__device__ __forceinline__ float sigmoid_f(float x) { return 1.f / (1.f + __expf(-x)); }
__device__ __forceinline__ float tanh_f(float x)    { return 1.f - 2.f / (1.f + __expf(2.f * x)); }
__device__ __forceinline__ half2_t mkh2(float a, float b) {
    half2_t r; r.x = (_Float16)a; r.y = (_Float16)b; return r;
}
__device__ __forceinline__ float h2get(unsigned u, int idx) {
    half2_t h = __builtin_bit_cast(half2_t, u);
    return idx ? (float)h.y : (float)h.x;
}
// barrier that drains only LDS (lgkm), NOT vmcnt: global stores/prefetches
// stay in flight across it.
#define BAR_LDS() asm volatile("s_waitcnt lgkmcnt(0)\n\ts_barrier" ::: "memory")

// Grid 256 x 1024, all co-resident (1 WG/CU).
//  bid <  64 : consumer — full GRU recurrence for batch=bid. 16 waves, k split
//              4-way; Wz/Wr h-part in VGPRs (64 half2), Wh h-part in LDS
//              (transposed+padded). LDS-only per-step exchange, lgkm-only barriers.
//  bid >= 64 : producer (gate g, batch b) — x-projections into a ring in ws,
//              RELAXED agent atomics + vmcnt drain before flag store.
extern "C" __global__ void __launch_bounds__(NTHR)
gru_fused(const float* __restrict__ x,
          const float* __restrict__ Wz, const float* __restrict__ bz,
          const float* __restrict__ Wr, const float* __restrict__ br,
          const float* __restrict__ Wh, const float* __restrict__ bh,
          float* __restrict__ out,
          unsigned* prodflag, unsigned* consflag,
          unsigned long long* preZR, unsigned* preH, int ring)
{
    __shared__ __align__(16) half2_t smem[LDS_UNITS];
    const int tid = threadIdx.x;
    const int bid = blockIdx.x;
    const int rmask = ring - 1;

    if (bid >= NB) {
        // ---------------- producer ----------------
        const int pb = bid - NB;        // 0..191
        const int g  = pb >> 6;         // 0=z 1=r 2=h
        const int b  = pb & 63;
        const float* W    = (g == 0) ? Wz : (g == 1) ? Wr : Wh;
        const float* bias = (g == 0) ? bz : (g == 1) ? br : bh;
        const int kh = tid & 1;         // k-half of 256 x-inputs
        const int c  = (tid >> 1) & 255;
        const int th = tid >> 9;        // 0..1 -> 16 steps each

        half2_t w2[64];                 // rows kh*128..+127 (x part), col c
        {
            const int kb = kh * 128;
            #pragma unroll
            for (int i = 0; i < 64; ++i)
                w2[i] = mkh2(W[(kb + 2*i) * NH + c], W[(kb + 2*i + 1) * NH + c]);
        }
        const float bv = bias[c];
        half2_t* xl = smem;             // 32 steps * 128 half2 = 4096 units

        for (int ch = 0; ch < NCHUNK; ++ch) {
            const int lead = ch * CHUNK + CHUNK - ring;
            if (lead > 0) {
                if (tid == 0) {
                    unsigned it = 0;
                    while ((int)__hip_atomic_load(&consflag[b], __ATOMIC_RELAXED,
                                                  __HIP_MEMORY_SCOPE_AGENT) < lead) {
                        __builtin_amdgcn_s_sleep(8);
                        if (++it > (1u << 20)) break;
                    }
                }
                __syncthreads();
            }
            const int t0 = ch * CHUNK;
            {
                const float4* xs = reinterpret_cast<const float4*>(
                    x + (size_t)b * NT * ND + (size_t)t0 * ND);
                #pragma unroll
                for (int rep = 0; rep < 2; ++rep) {
                    const int idx = rep * NTHR + tid;   // 0..2047 float4s
                    const float4 v = xs[idx];
                    xl[idx * 2]     = mkh2(v.x, v.y);
                    xl[idx * 2 + 1] = mkh2(v.z, v.w);
                }
            }
            __syncthreads();
            #pragma unroll 1
            for (int i = 0; i < 16; ++i) {
                const int tt = th * 16 + i;
                const half2_t* xr = &xl[tt * 128 + kh * 64];
                float a0 = 0.f, a1 = 0.f;
                #pragma unroll
                for (int k = 0; k < 32; ++k) {
                    a0 = __builtin_amdgcn_fdot2(xr[k],      w2[k],      a0, false);
                    a1 = __builtin_amdgcn_fdot2(xr[k + 32], w2[k + 32], a1, false);
                }
                float a = a0 + a1;
                a += __shfl_xor(a, 1, 64);   // combine k-halves
                a += bv;
                const float an = __shfl_xor(a, 2, 64);  // partner column c+1
                if (!(tid & 3)) {            // kh==0 && c even
                    const unsigned pk = __builtin_bit_cast(unsigned, mkh2(a, an));
                    const size_t slot = (size_t)b * ring + ((t0 + tt) & rmask);
                    if (g == 2) {
                        __hip_atomic_store(&preH[slot * 128 + (c >> 1)], pk,
                                           __ATOMIC_RELAXED, __HIP_MEMORY_SCOPE_AGENT);
                    } else {
                        unsigned* zr32 = reinterpret_cast<unsigned*>(&preZR[slot * 128 + (c >> 1)]);
                        __hip_atomic_store(&zr32[g], pk,
                                           __ATOMIC_RELAXED, __HIP_MEMORY_SCOPE_AGENT);
                    }
                }
            }
            asm volatile("s_waitcnt vmcnt(0)" ::: "memory");  // drain own stores
            __syncthreads();
            if (tid == 0)
                __hip_atomic_store(&prodflag[b * 3 + g], (unsigned)(ch + 1),
                                   __ATOMIC_RELAXED, __HIP_MEMORY_SCOPE_AGENT);
            __syncthreads();
        }
        return;
    }

    // ---------------- consumer: recurrence for batch b ----------------
    const int b   = bid;
    const int c   = tid >> 2;        // output column 0..255
    const int q   = tid & 3;         // k-quarter of the 256 h inputs
    const int sub = c & 1;           // half of the packed pre col-pair
    half2_t* hb = smem + 256 * WHH_STRIDE;   // [4][36]
    half2_t* vb = hb + 144;                  // [4][36]

    // stage Wh h-part transposed into LDS: whhT[c][kp] = (Wh[256+2kp][c], Wh[257+2kp][c])
    {
        const int cc = tid & 255;
        const int rp = tid >> 8;     // 0..3
        #pragma unroll
        for (int i = 0; i < 32; ++i) {
            const int kp = rp * 32 + i;
            smem[cc * WHH_STRIDE + kp] =
                mkh2(Wh[(ND + 2*kp) * NH + cc], Wh[(ND + 2*kp + 1) * NH + cc]);
        }
    }
    // register weights: Wz/Wr h-part, rows 256+q*64..+63, col c
    half2_t wzq[32], wrq[32];
    {
        const int kb = ND + q * 64;
        #pragma unroll
        for (int i = 0; i < 32; ++i) {
            wzq[i] = mkh2(Wz[(kb + 2*i) * NH + c], Wz[(kb + 2*i + 1) * NH + c]);
            wrq[i] = mkh2(Wr[(kb + 2*i) * NH + c], Wr[(kb + 2*i + 1) * NH + c]);
        }
    }
    {   // zero h/v buffers
        half2_t* hv = hb;
        if (tid < 288) hv[tid] = mkh2(0.f, 0.f);
    }
    float hreg = 0.f;

    // wait for chunk 0 of all 3 gates
    if (tid < 3) {
        unsigned it = 0;
        while (__hip_atomic_load(&prodflag[b * 3 + tid], __ATOMIC_RELAXED,
                                 __HIP_MEMORY_SCOPE_AGENT) < 1u) {
            __builtin_amdgcn_s_sleep(8);
            if (++it > (1u << 20)) break;
        }
    }
    __syncthreads();

    unsigned long long zr = __hip_atomic_load(&preZR[(size_t)b * ring * 128 + (c >> 1)],
                                              __ATOMIC_RELAXED, __HIP_MEMORY_SCOPE_AGENT);
    unsigned hh = __hip_atomic_load(&preH[(size_t)b * ring * 128 + (c >> 1)],
                                    __ATOMIC_RELAXED, __HIP_MEMORY_SCOPE_AGENT);
    float* outb = out + (size_t)b * NT * NH + c;

    for (int t = 0; t < NT; ++t) {
        const int tn = t + 1;
        const bool inchunk = (tn < NT) && ((tn & (CHUNK - 1)) != 0);
        unsigned long long zrn = 0; unsigned hhn = 0;
        if (inchunk) {   // prefetch next step's pre-activations (lands during this step)
            const size_t sl = ((size_t)b * ring + (tn & rmask)) * 128 + (c >> 1);
            zrn = __hip_atomic_load(&preZR[sl], __ATOMIC_RELAXED, __HIP_MEMORY_SCOPE_AGENT);
            hhn = __hip_atomic_load(&preH[sl], __ATOMIC_RELAXED, __HIP_MEMORY_SCOPE_AGENT);
        }

        // ---- stage A: z, r over this thread's 64 h-inputs (2 accums/gate) ----
        const half2_t* hsrc = hb + q * HV_STRIDE;
        float az0 = 0.f, az1 = 0.f, ar0 = 0.f, ar1 = 0.f;
        #pragma unroll
        for (int i = 0; i < 16; ++i) {
            const half2_t h0 = hsrc[i], h1 = hsrc[i + 16];
            az0 = __builtin_amdgcn_fdot2(h0, wzq[i],      az0, false);
            ar0 = __builtin_amdgcn_fdot2(h0, wrq[i],      ar0, false);
            az1 = __builtin_amdgcn_fdot2(h1, wzq[i + 16], az1, false);
            ar1 = __builtin_amdgcn_fdot2(h1, wrq[i + 16], ar1, false);
        }
        float az = az0 + az1, ar = ar0 + ar1;
        az += __shfl_xor(az, 1, 64); az += __shfl_xor(az, 2, 64);
        ar += __shfl_xor(ar, 1, 64); ar += __shfl_xor(ar, 2, 64);
        const float z = sigmoid_f(az + h2get((unsigned)(zr & 0xffffffffu), sub));
        const float r = sigmoid_f(ar + h2get((unsigned)(zr >> 32), sub));
        const float v  = r * hreg;
        const float v1 = __shfl_xor(v, 4, 64);   // partner column c+1
        if (!(tid & 7)) vb[(c >> 6) * HV_STRIDE + ((c & 63) >> 1)] = mkh2(v, v1);
        BAR_LDS();   // vb ready

        // ---- stage B: h_hat over v (Wh from LDS), then h_new ----
        const half2_t* vsrc = vb + q * HV_STRIDE;
        const half2_t* wb   = &smem[c * WHH_STRIDE + q * 32];
        float ah0 = 0.f, ah1 = 0.f;
        #pragma unroll
        for (int i = 0; i < 16; ++i) {
            ah0 = __builtin_amdgcn_fdot2(vsrc[i],      wb[i],      ah0, false);
            ah1 = __builtin_amdgcn_fdot2(vsrc[i + 16], wb[i + 16], ah1, false);
        }
        float ah = ah0 + ah1;
        ah += __shfl_xor(ah, 1, 64); ah += __shfl_xor(ah, 2, 64);
        const float hhat = tanh_f(ah + h2get(hh, sub));
        const float hn = hreg + z * (hhat - hreg);
        hreg = hn;
        if (q == 0) outb[(size_t)t * NH] = hn;
        const float hn1 = __shfl_xor(hn, 4, 64);
        if (!(tid & 7)) hb[(c >> 6) * HV_STRIDE + ((c & 63) >> 1)] = mkh2(hn, hn1);
        BAR_LDS();   // hb = h_t everywhere

        if (inchunk) {
            zr = zrn; hh = hhn;
        } else if (tn < NT) {
            if (tid == 0)   // publish progress (ring reuse gate)
                __hip_atomic_store(&consflag[b], (unsigned)tn,
                                   __ATOMIC_RELAXED, __HIP_MEMORY_SCOPE_AGENT);
            const unsigned need = (unsigned)((tn >> 5) + 1);
            if (tid < 3) {
                unsigned it = 0;
                while (__hip_atomic_load(&prodflag[b * 3 + tid], __ATOMIC_RELAXED,
                                         __HIP_MEMORY_SCOPE_AGENT) < need) {
                    __builtin_amdgcn_s_sleep(8);
                    if (++it > (1u << 20)) break;
                }
            }
            BAR_LDS();
            const size_t sl = ((size_t)b * ring + (tn & rmask)) * 128 + (c >> 1);
            zr = __hip_atomic_load(&preZR[sl], __ATOMIC_RELAXED, __HIP_MEMORY_SCOPE_AGENT);
            hh = __hip_atomic_load(&preH[sl], __ATOMIC_RELAXED, __HIP_MEMORY_SCOPE_AGENT);
        }
    }
}

extern "C" void kernel_launch(void* const* d_in, const int* in_sizes, int n_in,
                              void* d_out, int out_size, void* d_ws, size_t ws_size,
                              hipStream_t stream) {
    const float* x  = (const float*)d_in[0];
    const float* Wz = (const float*)d_in[1];
    const float* bz = (const float*)d_in[2];
    const float* Wr = (const float*)d_in[3];
    const float* br = (const float*)d_in[4];
    const float* Wh = (const float*)d_in[5];
    const float* bh = (const float*)d_in[6];
    float* outp = (float*)d_out;

    // ring sizing: per ring-step bytes = NB*128*12 = 96 KiB
    const size_t base = 4096;
    int ring = 32;
    for (int r = 2048; r >= 32; r >>= 1) {
        const size_t need = base + (size_t)NB * r * 128 * 12;
        if (need <= ws_size) { ring = r; break; }
    }
    char* w = (char*)d_ws;
    unsigned* prodflag = (unsigned*)w;                 // [64][3]
    unsigned* consflag = (unsigned*)(w + 1024);        // [64]
    unsigned long long* preZR = (unsigned long long*)(w + base);          // [64][ring][128]
    unsigned* preH = (unsigned*)(w + base + (size_t)NB * ring * 128 * 8); // [64][ring][128]

    hipMemsetAsync(w, 0, 4096, stream);  // flags must start at 0 each launch
    gru_fused<<<256, NTHR, 0, stream>>>(x, Wz, bz, Wr, br, Wh, bh, outp,
                                        prodflag, consflag, preZR, preH, ring);
}